// Round 12
// baseline (266.697 us; speedup 1.0000x reference)
//
#include <hip/hip_runtime.h>
#include <hip/hip_fp16.h>

// GCN: 3x (GEMM -> normalized adjacency aggregate) + mean-pool + MLP.
// R14 fixed-capacity bucket fill; 9 dispatches (288). R16 (278) gpool form.
// R17/R18 REGRESSED (358): XCD-pinned quartered gather; 4B/lane ->
//   instruction-overhead-bound. R19/R20 NEUTRAL (276). R21 REGRESSED (318):
//   single-pass fill = 4x write amplification. R22 (294): no-LDS GEMM +18us.
// R23 REGRESSED (287): block-split fill||gemm fusion (LDS tax on all branches).
// R24 (263.5) CHAMPION: gather loads 8B->16B/lane. CONFIRMED issue-limited:
//   -6.4us/gather. Lever = VMEM-inst count WHERE TLP abundant (1 node/wave).
// R25 REGRESSED (267.6): widening on gpool (+4): sequential-node -> reduce
//   chain is the cost. Reverted.
// R26 REGRESSED (302): gather->GEMM fusion @17.6% occ. Fusion CLOSED (x3).
// R27 NEUTRAL (265.8): fill grid 2048 — fill not wave-count-limited. Revert
//   to 1024.
// R28: same validated lever, one level deeper: bucket-index loads. A node's
//   CAP=64 bucket row = 256B contiguous -> ONE coalesced dword load
//   (bucket[beg+lane], 64 lanes) + __shfl(idx, min(slot,deg-1)) per use
//   replaces ~4 broadcast loads/chunk. VMEM inst/node: ~8*chunks -> 1+4*chunks.
//   Gather only (gpool untouched).
//   out[c] = dinv[c] * ( hs[c] + sum_{(r->c)} hs[r] ),  hs = (X@W) * dinv[row]

#define NGRAPH 100
#define CAP 64           // bucket slots per node

typedef _Float16 f16x8 __attribute__((ext_vector_type(8)));
typedef float f32x4 __attribute__((ext_vector_type(4)));
typedef float fx4 __attribute__((ext_vector_type(4)));   // builtin 16B vector for NT store

// ---------------- prep: Wt transpose-to-fp16 + zero cnt + zero pooled ----------------

__global__ __launch_bounds__(256) void prep_all(const float* __restrict__ W1,
                                                const float* __restrict__ W2,
                                                const float* __restrict__ W3,
                                                __half* __restrict__ Wt1,
                                                __half* __restrict__ Wt2,
                                                __half* __restrict__ Wt3,
                                                int* __restrict__ cnt,
                                                float* __restrict__ pooled, int n) {
    const int idx = blockIdx.x * 256 + threadIdx.x;    // 256 blocks = 65536 thr
    if (idx < 16384) {
        int nn = idx >> 7, k = idx & 127;
        Wt1[idx] = __float2half(W1[k * 128 + nn]);
    } else if (idx < 32768) {
        int j = idx - 16384;
        int nn = j >> 7, k = j & 127;
        Wt2[j] = __float2half(W2[k * 128 + nn]);
    } else if (idx < 40960) {
        int j = idx - 32768;
        int nn = j >> 7, k = j & 127;
        Wt3[j] = __float2half(W3[k * 64 + nn]);
    }
    if (idx < n) cnt[idx] = 0;                          // 65536 >= n
    if (idx < NGRAPH * 64) pooled[idx] = 0.0f;
}

// ---------------- bucket fill, col-partitioned (write locality per XCD) ----------

__global__ void fill_bucket(const int* __restrict__ row, const int* __restrict__ col,
                            int* __restrict__ cnt, int* __restrict__ bucket,
                            int E, int colsPerGroup) {
    const int g  = blockIdx.x & 7;
    const int gb = blockIdx.x >> 3;
    const int nb = gridDim.x >> 3;
    const int lo = g * colsPerGroup, hi = lo + colsPerGroup;
    for (int e = gb * 256 + threadIdx.x; e < E; e += nb * 256) {
        int c = col[e];
        if (c >= lo && c < hi) {
            int pos = atomicAdd(&cnt[c], 1);
            bucket[c * CAP + pos] = row[e];
        }
    }
}

// ---------------- MFMA GEMM (LDS form, proven): Yh = relu?(X+b) @ W * dinv[row] ----

template <int OUT, bool F16IN>
__global__ __launch_bounds__(256) void gemm_mfma(const void* __restrict__ Xv,
                                                 const __half* __restrict__ Wt,
                                                 const float* __restrict__ bias_in,
                                                 const int* __restrict__ cnt,
                                                 __half* __restrict__ Yh, int n) {
    __shared__ _Float16 Xs[64 * 128];
    __shared__ _Float16 Ws[OUT * 128];
    __shared__ float bs[128];

    const float*  Xf = (const float*)Xv;
    const __half* Xh = (const __half*)Xv;

    const int t = threadIdx.x;
    if (t < 128) bs[t] = (bias_in != nullptr) ? bias_in[t] : 0.0f;
    __syncthreads();

    const int row0 = blockIdx.x * 64;
    const bool do_relu = (bias_in != nullptr);

    for (int c = t; c < 64 * 16; c += 256) {
        const int r = c >> 4, q = c & 15;
        const int gr = row0 + r;
        float vals[8];
        #pragma unroll
        for (int i = 0; i < 8; ++i) vals[i] = 0.0f;
        if (gr < n) {
            if (F16IN) {
                f16x8 hv = *(const f16x8*)&Xh[(size_t)gr * 128 + q * 8];
                #pragma unroll
                for (int i = 0; i < 8; ++i) vals[i] = (float)hv[i];
            } else {
                float4 va = *(const float4*)&Xf[(size_t)gr * 128 + q * 8];
                float4 vb = *(const float4*)&Xf[(size_t)gr * 128 + q * 8 + 4];
                vals[0] = va.x; vals[1] = va.y; vals[2] = va.z; vals[3] = va.w;
                vals[4] = vb.x; vals[5] = vb.y; vals[6] = vb.z; vals[7] = vb.w;
            }
        }
        if (do_relu) {
            const int k = q * 8;
            #pragma unroll
            for (int i = 0; i < 8; ++i) vals[i] = fmaxf(vals[i] + bs[k + i], 0.f);
        }
        f16x8 hv;
        #pragma unroll
        for (int i = 0; i < 8; ++i) hv[i] = (_Float16)vals[i];
        *(f16x8*)&Xs[(size_t)((r << 4) + (q ^ (r & 15))) * 8] = hv;
    }
    for (int c = t; c < OUT * 16; c += 256) {
        const int nn = c >> 4, q = c & 15;
        f16x8 w = *(const f16x8*)&Wt[nn * 128 + q * 8];
        *(f16x8*)&Ws[(size_t)((nn << 4) + (q ^ (nn & 15))) * 8] = w;
    }
    __syncthreads();

    constexpr int NT = OUT / 16;
    const int lane = t & 63, wave = t >> 6;
    const int m = lane & 15, quad = lane >> 4;

    f32x4 acc[NT];
    #pragma unroll
    for (int i = 0; i < NT; ++i) acc[i] = (f32x4){0.f, 0.f, 0.f, 0.f};

    #pragma unroll
    for (int s = 0; s < 4; ++s) {
        const int qa = s * 4 + quad;
        f16x8 a = *(const f16x8*)&Xs[(size_t)(((wave * 16 + m) << 4) + (qa ^ m)) * 8];
        #pragma unroll
        for (int tt = 0; tt < NT; ++tt) {
            f16x8 b = *(const f16x8*)&Ws[(size_t)(((tt * 16 + m) << 4) + (qa ^ m)) * 8];
            acc[tt] = __builtin_amdgcn_mfma_f32_16x16x32_f16(a, b, acc[tt], 0, 0, 0);
        }
    }

    #pragma unroll
    for (int i = 0; i < 4; ++i) {
        const int gr = row0 + wave * 16 + quad * 4 + i;
        if (gr < n) {
            const float dw = 1.0f / sqrtf((float)(cnt[gr] + 1));
            #pragma unroll
            for (int tt = 0; tt < NT; ++tt)
                Yh[(size_t)gr * OUT + tt * 16 + m] = __float2half(acc[tt][i] * dw);
        }
    }
}

// ---------------- gather<128>: 4 streams x 16 lanes x 16B; reg-resident bucket ----
// R28: ONE coalesced dword load grabs the node's whole 256B bucket row into
// registers (bucket[beg+lane]); per-use neighbor index via __shfl with source
// lane clamped to deg-1 (valid addr for uninit slots; FMA mask zeroes them).
// Slot mapping (bijective): slot = t*16 + strm + 4k, strm in [0,4), k in [0,4).

template <int F>
__global__ void gather_kernel(const __half* __restrict__ hs, const int* __restrict__ cnt,
                              const int* __restrict__ bucket,
                              __half* __restrict__ outh, int n) {
    const int lane = threadIdx.x & 63;
    const int c = (blockIdx.x * blockDim.x + threadIdx.x) >> 6;
    if (c >= n) return;
    const int deg = cnt[c];
    const int beg = c * CAP;
    const float w = 1.0f / sqrtf((float)(deg + 1));
    const float4* hq = (const float4*)hs;     // row = 16 x 16B

    const int strm = lane >> 4;               // 4 neighbor streams
    const int li   = lane & 15;               // 16B slot within 256B row

    // one instruction: the whole bucket row (slots 0..63) into wave registers
    const int idxReg = __builtin_nontemporal_load(&bucket[beg + lane]);

    float a[8];
    #pragma unroll
    for (int i = 0; i < 8; ++i) a[i] = 0.f;

    auto acc8 = [&](float4 raw, float m) {
        __half2 h0 = *(__half2*)&raw.x;
        __half2 h1 = *(__half2*)&raw.y;
        __half2 h2 = *(__half2*)&raw.z;
        __half2 h3 = *(__half2*)&raw.w;
        float2 f0 = __half22float2(h0), f1 = __half22float2(h1);
        float2 f2 = __half22float2(h2), f3 = __half22float2(h3);
        a[0] += m * f0.x; a[1] += m * f0.y;
        a[2] += m * f1.x; a[3] += m * f1.y;
        a[4] += m * f2.x; a[5] += m * f2.y;
        a[6] += m * f3.x; a[7] += m * f3.y;
    };

    if (strm == 0) acc8(hq[(size_t)c * 16 + li], 1.f);    // self-loop

    const int chunks = (deg + 15) >> 4;                   // <= 4 (16 nbrs/chunk)
    const int dm = deg - 1;                               // valid when chunks >= 1
    for (int t = 0; t < chunks; ++t) {
        const int sl0 = t * 16 + strm;
        const int sl1 = sl0 + 4, sl2 = sl0 + 8, sl3 = sl0 + 12;
        const int s0 = __shfl(idxReg, min(sl0, dm));
        const int s1 = __shfl(idxReg, min(sl1, dm));
        const int s2 = __shfl(idxReg, min(sl2, dm));
        const int s3 = __shfl(idxReg, min(sl3, dm));
        const float m0 = (sl0 <= dm) ? 1.f : 0.f;
        const float m1 = (sl1 <= dm) ? 1.f : 0.f;
        const float m2 = (sl2 <= dm) ? 1.f : 0.f;
        const float m3 = (sl3 <= dm) ? 1.f : 0.f;
        float4 v0 = hq[(size_t)s0 * 16 + li];
        float4 v1 = hq[(size_t)s1 * 16 + li];
        float4 v2 = hq[(size_t)s2 * 16 + li];
        float4 v3 = hq[(size_t)s3 * 16 + li];
        acc8(v0, m0);
        acc8(v1, m1);
        acc8(v2, m2);
        acc8(v3, m3);
    }

    #pragma unroll
    for (int i = 0; i < 8; ++i) {
        a[i] += __shfl(a[i], lane ^ 16);      // streams 0+1 / 2+3
        a[i] += __shfl(a[i], lane ^ 32);      // pairs
    }
    if (strm == 0) {
        __half2 o0 = __float22half2_rn(make_float2(w * a[0], w * a[1]));
        __half2 o1 = __float22half2_rn(make_float2(w * a[2], w * a[3]));
        __half2 o2 = __float22half2_rn(make_float2(w * a[4], w * a[5]));
        __half2 o3 = __float22half2_rn(make_float2(w * a[6], w * a[7]));
        fx4 o;
        o[0] = *(float*)&o0;
        o[1] = *(float*)&o1;
        o[2] = *(float*)&o2;
        o[3] = *(float*)&o3;
        __builtin_nontemporal_store(o, (fx4*)&outh[(size_t)c * 128 + li * 8]);
    }
}

// ---------------- fused gather(64) + pool: R24 champion form ----------------
// 2 half-wave streams x 32 lanes x dword; 8-deep; predicated chunks.
// Boundary-flush atomics (batch sorted -> wave-uniform). NO fences (R15).

__global__ __launch_bounds__(256) void fused_gpool(const __half* __restrict__ hs,
                                                   const int* __restrict__ cnt,
                                                   const int* __restrict__ bucket,
                                                   const float* __restrict__ b3,
                                                   const int* __restrict__ batch,
                                                   float* __restrict__ pooled, int n) {
    const int lane  = threadIdx.x & 63;
    const int half  = lane >> 5;               // edge stream id
    const int li    = lane & 31;               // dword index in 64-feat row
    const int wave  = (blockIdx.x * blockDim.x + threadIdx.x) >> 6;
    const int nwav  = (gridDim.x * blockDim.x) >> 6;
    const int chunk = (n + nwav - 1) / nwav;
    const int beg = wave * chunk;
    const int end = min(beg + chunk, n);
    if (beg >= end) return;
    const unsigned* h2 = (const unsigned*)hs;  // row = 32 dwords

    auto cvt2 = [](unsigned raw) { return __half22float2(*(__half2*)&raw); };

    const float bias0 = b3[li * 2], bias1 = b3[li * 2 + 1];
    int curg = batch[beg];
    float2 acc = make_float2(0.f, 0.f);
    for (int i = beg; i < end; ++i) {
        int g = batch[i];                      // wave-uniform
        if (g != curg) {
            if (half == 0) {
                atomicAdd(&pooled[curg * 64 + li * 2],     acc.x);
                atomicAdd(&pooled[curg * 64 + li * 2 + 1], acc.y);
            }
            acc = make_float2(0.f, 0.f); curg = g;
        }
        const int deg = cnt[i];
        const float dv = 1.0f / sqrtf((float)(deg + 1));
        float2 sv = make_float2(0.f, 0.f);
        if (half == 0) sv = cvt2(h2[(size_t)i * 32 + li]);   // self-loop
        const int eb = i * CAP, ee = eb + deg;
        const int lastj = ee - 1;
        const int chks = (deg + 15) >> 4;                    // <= 4
        int j = eb + half;
        for (int t = 0; t < chks; ++t, j += 16) {
            const int j0 = j,      j1 = j + 2,  j2 = j + 4,  j3 = j + 6;
            const int j4 = j + 8,  j5 = j + 10, j6 = j + 12, j7 = j + 14;
            const int a0 = __builtin_nontemporal_load(&bucket[min(j0, lastj)]);
            const int a1 = __builtin_nontemporal_load(&bucket[min(j1, lastj)]);
            const int a2 = __builtin_nontemporal_load(&bucket[min(j2, lastj)]);
            const int a3 = __builtin_nontemporal_load(&bucket[min(j3, lastj)]);
            const int a4 = __builtin_nontemporal_load(&bucket[min(j4, lastj)]);
            const int a5 = __builtin_nontemporal_load(&bucket[min(j5, lastj)]);
            const int a6 = __builtin_nontemporal_load(&bucket[min(j6, lastj)]);
            const int a7 = __builtin_nontemporal_load(&bucket[min(j7, lastj)]);
            const float m0 = (j0 < ee) ? 1.f : 0.f;
            const float m1 = (j1 < ee) ? 1.f : 0.f;
            const float m2 = (j2 < ee) ? 1.f : 0.f;
            const float m3 = (j3 < ee) ? 1.f : 0.f;
            const float m4 = (j4 < ee) ? 1.f : 0.f;
            const float m5 = (j5 < ee) ? 1.f : 0.f;
            const float m6 = (j6 < ee) ? 1.f : 0.f;
            const float m7 = (j7 < ee) ? 1.f : 0.f;
            float2 v0 = cvt2(h2[(size_t)a0 * 32 + li]);
            float2 v1 = cvt2(h2[(size_t)a1 * 32 + li]);
            float2 v2 = cvt2(h2[(size_t)a2 * 32 + li]);
            float2 v3 = cvt2(h2[(size_t)a3 * 32 + li]);
            float2 v4 = cvt2(h2[(size_t)a4 * 32 + li]);
            float2 v5 = cvt2(h2[(size_t)a5 * 32 + li]);
            float2 v6 = cvt2(h2[(size_t)a6 * 32 + li]);
            float2 v7 = cvt2(h2[(size_t)a7 * 32 + li]);
            sv.x += m0 * v0.x + m1 * v1.x + m2 * v2.x + m3 * v3.x
                  + m4 * v4.x + m5 * v5.x + m6 * v6.x + m7 * v7.x;
            sv.y += m0 * v0.y + m1 * v1.y + m2 * v2.y + m3 * v3.y
                  + m4 * v4.y + m5 * v5.y + m6 * v6.y + m7 * v7.y;
        }
        sv.x += __shfl(sv.x, lane ^ 32);       // combine streams
        sv.y += __shfl(sv.y, lane ^ 32);
        acc.x += fmaxf(dv * sv.x + bias0, 0.f);
        acc.y += fmaxf(dv * sv.y + bias1, 0.f);
    }
    if (half == 0) {
        atomicAdd(&pooled[curg * 64 + li * 2],     acc.x);
        atomicAdd(&pooled[curg * 64 + li * 2 + 1], acc.y);
    }
}

// ---------------- mean + 64->32->10 MLP ----------------

__global__ __launch_bounds__(64) void mlp_kernel(const float* __restrict__ pooled,
                                                 const int* __restrict__ batch,
                                                 const float* __restrict__ Wf1,
                                                 const float* __restrict__ bf1,
                                                 const float* __restrict__ Wf2,
                                                 const float* __restrict__ bf2,
                                                 float* __restrict__ out, int n) {
    const int g = blockIdx.x;
    const int t = threadIdx.x;

    auto lb = [&](int v) {
        int lo = 0, hi = n;
        while (lo < hi) { int mid = (lo + hi) >> 1; if (batch[mid] < v) lo = mid + 1; else hi = mid; }
        return lo;
    };
    const int cnt = lb(g + 1) - lb(g);

    __shared__ float pm[64];
    __shared__ float hid[32];

    pm[t] = pooled[g * 64 + t] / (float)(cnt > 0 ? cnt : 1);
    __syncthreads();

    if (t < 32) {
        float a = bf1[t];
        #pragma unroll
        for (int k = 0; k < 64; ++k) a += pm[k] * Wf1[k * 32 + t];
        hid[t] = fmaxf(a, 0.f);
    }
    __syncthreads();

    if (t < 10) {
        float a = bf2[t];
        #pragma unroll
        for (int k = 0; k < 32; ++k) a += hid[k] * Wf2[k * 10 + t];
        out[g * 10 + t] = a;
    }
}

// ---------------- launcher ----------------

extern "C" void kernel_launch(void* const* d_in, const int* in_sizes, int n_in,
                              void* d_out, int out_size, void* d_ws, size_t ws_size,
                              hipStream_t stream) {
    const float* x     = (const float*)d_in[0];
    const int*   edge  = (const int*)  d_in[1];
    const int*   batch = (const int*)  d_in[2];
    const float* W1    = (const float*)d_in[3];
    const float* b1    = (const float*)d_in[4];
    const float* W2    = (const float*)d_in[5];
    const float* b2    = (const float*)d_in[6];
    const float* W3    = (const float*)d_in[7];
    const float* b3    = (const float*)d_in[8];
    const float* Wf1   = (const float*)d_in[9];
    const float* bf1   = (const float*)d_in[10];
    const float* Wf2   = (const float*)d_in[11];
    const float* bf2   = (const float*)d_in[12];
    float* out = (float*)d_out;

    const int E = in_sizes[1] / 2;     // 800000
    const int n = in_sizes[2];         // 50000
    const int* row = edge;
    const int* col = edge + E;

    const int colsPerGroup = (n + 7) / 8;                  // 6250

    const size_t n_pad = ((size_t)n + 64) & ~(size_t)63;
    char* wsb = (char*)d_ws;
    int*    cnt    = (int*)wsb;                  wsb += n_pad * 4;            // degree
    float*  pooled = (float*)wsb;                wsb += NGRAPH * 64 * 4;
    int*    bucket = (int*)wsb;                  wsb += (size_t)n_pad * CAP * 4;  // 12.8 MB
    __half* Wt1    = (__half*)wsb;               wsb += 16384 * 2;
    __half* Wt2    = (__half*)wsb;               wsb += 16384 * 2;
    __half* Wt3    = (__half*)wsb;               wsb += 8192 * 2;
    __half* bufA   = (__half*)wsb;               wsb += (size_t)n * 128 * 2;  // 12.8 MB
    __half* bufB   = (__half*)wsb;                                            // 12.8 MB

    // ---- prep + bucket build ----
    prep_all<<<256, 256, 0, stream>>>(W1, W2, W3, Wt1, Wt2, Wt3, cnt, pooled, n);
    fill_bucket<<<1024, 256, 0, stream>>>(row, col, cnt, bucket, E, colsPerGroup);

    const int ggemm = (n + 63) / 64;                       // 64 rows per block
    const int gath_grid = (n * 64 + 255) / 256;            // one wave per node

    // layer 1 (fp32 input)
    gemm_mfma<128, false><<<ggemm, 256, 0, stream>>>(x, Wt1, nullptr, cnt, bufA, n);
    gather_kernel<128><<<gath_grid, 256, 0, stream>>>(bufA, cnt, bucket, bufB, n);
    // layer 2 (fp16 input)
    gemm_mfma<128, true><<<ggemm, 256, 0, stream>>>(bufB, Wt2, b1, cnt, bufA, n);
    gather_kernel<128><<<gath_grid, 256, 0, stream>>>(bufA, cnt, bucket, bufB, n);
    // layer 3 (64-wide, fp16 input)
    gemm_mfma<64, true><<<ggemm, 256, 0, stream>>>(bufB, Wt3, b2, cnt, bufA, n);
    // head: gather64 + relu(+b3) + mean-pool fused; then MLP
    fused_gpool<<<2048, 256, 0, stream>>>(bufA, cnt, bucket, b3, batch, pooled, n);
    mlp_kernel<<<NGRAPH, 64, 0, stream>>>(pooled, batch, Wf1, bf1, Wf2, bf2, out, n);
}

// Round 13
// 259.508 us; speedup vs baseline: 1.0277x; 1.0277x over previous
//
#include <hip/hip_runtime.h>
#include <hip/hip_fp16.h>

// GCN: 3x (GEMM -> normalized adjacency aggregate) + mean-pool + MLP.
// R14 fixed-capacity bucket fill; 9 dispatches (288). R16 (278) gpool form.
// R17/R18 REGRESSED (358): XCD-pinned quartered gather; 4B/lane ->
//   instruction-overhead-bound. R19/R20 NEUTRAL (276): predication + NT
//   hints bundled, never isolated. R21 REGRESSED (318): single-pass fill.
// R22 (294): no-LDS GEMM +18us. R23 REGRESSED (287): block-split fusion.
// R24 (263.5) CHAMPION: gather loads 8B->16B/lane. Issue-limited confirmed.
// R25 REGRESSED (267.6): widening on gpool (sequential-node reduce chain).
// R26 REGRESSED (302): gather->GEMM fusion @17.6% occ. Fusion CLOSED (x3).
//   KEY COUNTER: FETCH=78MB for ~13MB compulsory -> NT-stored hs was
//   HBM-cold for the consumer.
// R27 NEUTRAL (265.8): fill grid 2048. R28 NEUTRAL- (266.7): reg-bucket+shfl
//   (broadcast index loads were free; gather is row-load-bound).
// R29: R24-exact minus ALL nontemporal hints (isolating R19's bundle).
//   NT stores push the 12.8MB inter-layer buf to HBM (evict-first) and NT
//   bucket loads block cross-kernel L2 retention of the 12.8MB bucket that
//   3 kernels re-stream. Plain loads/stores; zero other changes.
//   out[c] = dinv[c] * ( hs[c] + sum_{(r->c)} hs[r] ),  hs = (X@W) * dinv[row]

#define NGRAPH 100
#define CAP 64           // bucket slots per node

typedef _Float16 f16x8 __attribute__((ext_vector_type(8)));
typedef float f32x4 __attribute__((ext_vector_type(4)));

// ---------------- prep: Wt transpose-to-fp16 + zero cnt + zero pooled ----------------

__global__ __launch_bounds__(256) void prep_all(const float* __restrict__ W1,
                                                const float* __restrict__ W2,
                                                const float* __restrict__ W3,
                                                __half* __restrict__ Wt1,
                                                __half* __restrict__ Wt2,
                                                __half* __restrict__ Wt3,
                                                int* __restrict__ cnt,
                                                float* __restrict__ pooled, int n) {
    const int idx = blockIdx.x * 256 + threadIdx.x;    // 256 blocks = 65536 thr
    if (idx < 16384) {
        int nn = idx >> 7, k = idx & 127;
        Wt1[idx] = __float2half(W1[k * 128 + nn]);
    } else if (idx < 32768) {
        int j = idx - 16384;
        int nn = j >> 7, k = j & 127;
        Wt2[j] = __float2half(W2[k * 128 + nn]);
    } else if (idx < 40960) {
        int j = idx - 32768;
        int nn = j >> 7, k = j & 127;
        Wt3[j] = __float2half(W3[k * 64 + nn]);
    }
    if (idx < n) cnt[idx] = 0;                          // 65536 >= n
    if (idx < NGRAPH * 64) pooled[idx] = 0.0f;
}

// ---------------- bucket fill, col-partitioned (write locality per XCD) ----------

__global__ void fill_bucket(const int* __restrict__ row, const int* __restrict__ col,
                            int* __restrict__ cnt, int* __restrict__ bucket,
                            int E, int colsPerGroup) {
    const int g  = blockIdx.x & 7;
    const int gb = blockIdx.x >> 3;
    const int nb = gridDim.x >> 3;
    const int lo = g * colsPerGroup, hi = lo + colsPerGroup;
    for (int e = gb * 256 + threadIdx.x; e < E; e += nb * 256) {
        int c = col[e];
        if (c >= lo && c < hi) {
            int pos = atomicAdd(&cnt[c], 1);
            bucket[c * CAP + pos] = row[e];
        }
    }
}

// ---------------- MFMA GEMM (LDS form, proven): Yh = relu?(X+b) @ W * dinv[row] ----

template <int OUT, bool F16IN>
__global__ __launch_bounds__(256) void gemm_mfma(const void* __restrict__ Xv,
                                                 const __half* __restrict__ Wt,
                                                 const float* __restrict__ bias_in,
                                                 const int* __restrict__ cnt,
                                                 __half* __restrict__ Yh, int n) {
    __shared__ _Float16 Xs[64 * 128];
    __shared__ _Float16 Ws[OUT * 128];
    __shared__ float bs[128];

    const float*  Xf = (const float*)Xv;
    const __half* Xh = (const __half*)Xv;

    const int t = threadIdx.x;
    if (t < 128) bs[t] = (bias_in != nullptr) ? bias_in[t] : 0.0f;
    __syncthreads();

    const int row0 = blockIdx.x * 64;
    const bool do_relu = (bias_in != nullptr);

    for (int c = t; c < 64 * 16; c += 256) {
        const int r = c >> 4, q = c & 15;
        const int gr = row0 + r;
        float vals[8];
        #pragma unroll
        for (int i = 0; i < 8; ++i) vals[i] = 0.0f;
        if (gr < n) {
            if (F16IN) {
                f16x8 hv = *(const f16x8*)&Xh[(size_t)gr * 128 + q * 8];
                #pragma unroll
                for (int i = 0; i < 8; ++i) vals[i] = (float)hv[i];
            } else {
                float4 va = *(const float4*)&Xf[(size_t)gr * 128 + q * 8];
                float4 vb = *(const float4*)&Xf[(size_t)gr * 128 + q * 8 + 4];
                vals[0] = va.x; vals[1] = va.y; vals[2] = va.z; vals[3] = va.w;
                vals[4] = vb.x; vals[5] = vb.y; vals[6] = vb.z; vals[7] = vb.w;
            }
        }
        if (do_relu) {
            const int k = q * 8;
            #pragma unroll
            for (int i = 0; i < 8; ++i) vals[i] = fmaxf(vals[i] + bs[k + i], 0.f);
        }
        f16x8 hv;
        #pragma unroll
        for (int i = 0; i < 8; ++i) hv[i] = (_Float16)vals[i];
        *(f16x8*)&Xs[(size_t)((r << 4) + (q ^ (r & 15))) * 8] = hv;
    }
    for (int c = t; c < OUT * 16; c += 256) {
        const int nn = c >> 4, q = c & 15;
        f16x8 w = *(const f16x8*)&Wt[nn * 128 + q * 8];
        *(f16x8*)&Ws[(size_t)((nn << 4) + (q ^ (nn & 15))) * 8] = w;
    }
    __syncthreads();

    constexpr int NT = OUT / 16;
    const int lane = t & 63, wave = t >> 6;
    const int m = lane & 15, quad = lane >> 4;

    f32x4 acc[NT];
    #pragma unroll
    for (int i = 0; i < NT; ++i) acc[i] = (f32x4){0.f, 0.f, 0.f, 0.f};

    #pragma unroll
    for (int s = 0; s < 4; ++s) {
        const int qa = s * 4 + quad;
        f16x8 a = *(const f16x8*)&Xs[(size_t)(((wave * 16 + m) << 4) + (qa ^ m)) * 8];
        #pragma unroll
        for (int tt = 0; tt < NT; ++tt) {
            f16x8 b = *(const f16x8*)&Ws[(size_t)(((tt * 16 + m) << 4) + (qa ^ m)) * 8];
            acc[tt] = __builtin_amdgcn_mfma_f32_16x16x32_f16(a, b, acc[tt], 0, 0, 0);
        }
    }

    #pragma unroll
    for (int i = 0; i < 4; ++i) {
        const int gr = row0 + wave * 16 + quad * 4 + i;
        if (gr < n) {
            const float dw = 1.0f / sqrtf((float)(cnt[gr] + 1));
            #pragma unroll
            for (int tt = 0; tt < NT; ++tt)
                Yh[(size_t)gr * OUT + tt * 16 + m] = __float2half(acc[tt][i] * dw);
        }
    }
}

// ---------------- gather<128>: 4 streams x 16 lanes x 16B, predicated chunks ----------
// R24 champion geometry; R29: plain (cached) loads/stores, no NT hints.

template <int F>
__global__ void gather_kernel(const __half* __restrict__ hs, const int* __restrict__ cnt,
                              const int* __restrict__ bucket,
                              __half* __restrict__ outh, int n) {
    const int lane = threadIdx.x & 63;
    const int c = (blockIdx.x * blockDim.x + threadIdx.x) >> 6;
    if (c >= n) return;
    const int deg = cnt[c];
    const int beg = c * CAP;
    const int end = beg + deg;
    const int last = end - 1;                 // valid whenever deg >= 1
    const float w = 1.0f / sqrtf((float)(deg + 1));
    const float4* hq = (const float4*)hs;     // row = 16 x 16B

    const int strm = lane >> 4;               // 4 neighbor streams
    const int li   = lane & 15;               // 16B slot within 256B row

    float a[8];
    #pragma unroll
    for (int i = 0; i < 8; ++i) a[i] = 0.f;

    auto acc8 = [&](float4 raw, float m) {
        __half2 h0 = *(__half2*)&raw.x;
        __half2 h1 = *(__half2*)&raw.y;
        __half2 h2 = *(__half2*)&raw.z;
        __half2 h3 = *(__half2*)&raw.w;
        float2 f0 = __half22float2(h0), f1 = __half22float2(h1);
        float2 f2 = __half22float2(h2), f3 = __half22float2(h3);
        a[0] += m * f0.x; a[1] += m * f0.y;
        a[2] += m * f1.x; a[3] += m * f1.y;
        a[4] += m * f2.x; a[5] += m * f2.y;
        a[6] += m * f3.x; a[7] += m * f3.y;
    };

    if (strm == 0) acc8(hq[(size_t)c * 16 + li], 1.f);    // self-loop

    const int chunks = (deg + 15) >> 4;                   // <= 4 (16 nbrs/chunk)
    int j = beg + strm;
    for (int t = 0; t < chunks; ++t, j += 16) {
        const int j0 = j, j1 = j + 4, j2 = j + 8, j3 = j + 12;
        const int s0 = bucket[min(j0, last)];
        const int s1 = bucket[min(j1, last)];
        const int s2 = bucket[min(j2, last)];
        const int s3 = bucket[min(j3, last)];
        const float m0 = (j0 < end) ? 1.f : 0.f;
        const float m1 = (j1 < end) ? 1.f : 0.f;
        const float m2 = (j2 < end) ? 1.f : 0.f;
        const float m3 = (j3 < end) ? 1.f : 0.f;
        float4 v0 = hq[(size_t)s0 * 16 + li];
        float4 v1 = hq[(size_t)s1 * 16 + li];
        float4 v2 = hq[(size_t)s2 * 16 + li];
        float4 v3 = hq[(size_t)s3 * 16 + li];
        acc8(v0, m0);
        acc8(v1, m1);
        acc8(v2, m2);
        acc8(v3, m3);
    }

    #pragma unroll
    for (int i = 0; i < 8; ++i) {
        a[i] += __shfl(a[i], lane ^ 16);      // streams 0+1 / 2+3
        a[i] += __shfl(a[i], lane ^ 32);      // pairs
    }
    if (strm == 0) {
        __half2 o0 = __float22half2_rn(make_float2(w * a[0], w * a[1]));
        __half2 o1 = __float22half2_rn(make_float2(w * a[2], w * a[3]));
        __half2 o2 = __float22half2_rn(make_float2(w * a[4], w * a[5]));
        __half2 o3 = __float22half2_rn(make_float2(w * a[6], w * a[7]));
        float4 o;
        o.x = *(float*)&o0;
        o.y = *(float*)&o1;
        o.z = *(float*)&o2;
        o.w = *(float*)&o3;
        *(float4*)&outh[(size_t)c * 128 + li * 8] = o;
    }
}

// ---------------- fused gather(64) + pool: R24 champion form, no NT ----------------
// 2 half-wave streams x 32 lanes x dword; 8-deep; predicated chunks.
// Boundary-flush atomics (batch sorted -> wave-uniform). NO fences (R15).

__global__ __launch_bounds__(256) void fused_gpool(const __half* __restrict__ hs,
                                                   const int* __restrict__ cnt,
                                                   const int* __restrict__ bucket,
                                                   const float* __restrict__ b3,
                                                   const int* __restrict__ batch,
                                                   float* __restrict__ pooled, int n) {
    const int lane  = threadIdx.x & 63;
    const int half  = lane >> 5;               // edge stream id
    const int li    = lane & 31;               // dword index in 64-feat row
    const int wave  = (blockIdx.x * blockDim.x + threadIdx.x) >> 6;
    const int nwav  = (gridDim.x * blockDim.x) >> 6;
    const int chunk = (n + nwav - 1) / nwav;
    const int beg = wave * chunk;
    const int end = min(beg + chunk, n);
    if (beg >= end) return;
    const unsigned* h2 = (const unsigned*)hs;  // row = 32 dwords

    auto cvt2 = [](unsigned raw) { return __half22float2(*(__half2*)&raw); };

    const float bias0 = b3[li * 2], bias1 = b3[li * 2 + 1];
    int curg = batch[beg];
    float2 acc = make_float2(0.f, 0.f);
    for (int i = beg; i < end; ++i) {
        int g = batch[i];                      // wave-uniform
        if (g != curg) {
            if (half == 0) {
                atomicAdd(&pooled[curg * 64 + li * 2],     acc.x);
                atomicAdd(&pooled[curg * 64 + li * 2 + 1], acc.y);
            }
            acc = make_float2(0.f, 0.f); curg = g;
        }
        const int deg = cnt[i];
        const float dv = 1.0f / sqrtf((float)(deg + 1));
        float2 sv = make_float2(0.f, 0.f);
        if (half == 0) sv = cvt2(h2[(size_t)i * 32 + li]);   // self-loop
        const int eb = i * CAP, ee = eb + deg;
        const int lastj = ee - 1;
        const int chks = (deg + 15) >> 4;                    // <= 4
        int j = eb + half;
        for (int t = 0; t < chks; ++t, j += 16) {
            const int j0 = j,      j1 = j + 2,  j2 = j + 4,  j3 = j + 6;
            const int j4 = j + 8,  j5 = j + 10, j6 = j + 12, j7 = j + 14;
            const int a0 = bucket[min(j0, lastj)];
            const int a1 = bucket[min(j1, lastj)];
            const int a2 = bucket[min(j2, lastj)];
            const int a3 = bucket[min(j3, lastj)];
            const int a4 = bucket[min(j4, lastj)];
            const int a5 = bucket[min(j5, lastj)];
            const int a6 = bucket[min(j6, lastj)];
            const int a7 = bucket[min(j7, lastj)];
            const float m0 = (j0 < ee) ? 1.f : 0.f;
            const float m1 = (j1 < ee) ? 1.f : 0.f;
            const float m2 = (j2 < ee) ? 1.f : 0.f;
            const float m3 = (j3 < ee) ? 1.f : 0.f;
            const float m4 = (j4 < ee) ? 1.f : 0.f;
            const float m5 = (j5 < ee) ? 1.f : 0.f;
            const float m6 = (j6 < ee) ? 1.f : 0.f;
            const float m7 = (j7 < ee) ? 1.f : 0.f;
            float2 v0 = cvt2(h2[(size_t)a0 * 32 + li]);
            float2 v1 = cvt2(h2[(size_t)a1 * 32 + li]);
            float2 v2 = cvt2(h2[(size_t)a2 * 32 + li]);
            float2 v3 = cvt2(h2[(size_t)a3 * 32 + li]);
            float2 v4 = cvt2(h2[(size_t)a4 * 32 + li]);
            float2 v5 = cvt2(h2[(size_t)a5 * 32 + li]);
            float2 v6 = cvt2(h2[(size_t)a6 * 32 + li]);
            float2 v7 = cvt2(h2[(size_t)a7 * 32 + li]);
            sv.x += m0 * v0.x + m1 * v1.x + m2 * v2.x + m3 * v3.x
                  + m4 * v4.x + m5 * v5.x + m6 * v6.x + m7 * v7.x;
            sv.y += m0 * v0.y + m1 * v1.y + m2 * v2.y + m3 * v3.y
                  + m4 * v4.y + m5 * v5.y + m6 * v6.y + m7 * v7.y;
        }
        sv.x += __shfl(sv.x, lane ^ 32);       // combine streams
        sv.y += __shfl(sv.y, lane ^ 32);
        acc.x += fmaxf(dv * sv.x + bias0, 0.f);
        acc.y += fmaxf(dv * sv.y + bias1, 0.f);
    }
    if (half == 0) {
        atomicAdd(&pooled[curg * 64 + li * 2],     acc.x);
        atomicAdd(&pooled[curg * 64 + li * 2 + 1], acc.y);
    }
}

// ---------------- mean + 64->32->10 MLP ----------------

__global__ __launch_bounds__(64) void mlp_kernel(const float* __restrict__ pooled,
                                                 const int* __restrict__ batch,
                                                 const float* __restrict__ Wf1,
                                                 const float* __restrict__ bf1,
                                                 const float* __restrict__ Wf2,
                                                 const float* __restrict__ bf2,
                                                 float* __restrict__ out, int n) {
    const int g = blockIdx.x;
    const int t = threadIdx.x;

    auto lb = [&](int v) {
        int lo = 0, hi = n;
        while (lo < hi) { int mid = (lo + hi) >> 1; if (batch[mid] < v) lo = mid + 1; else hi = mid; }
        return lo;
    };
    const int cnt = lb(g + 1) - lb(g);

    __shared__ float pm[64];
    __shared__ float hid[32];

    pm[t] = pooled[g * 64 + t] / (float)(cnt > 0 ? cnt : 1);
    __syncthreads();

    if (t < 32) {
        float a = bf1[t];
        #pragma unroll
        for (int k = 0; k < 64; ++k) a += pm[k] * Wf1[k * 32 + t];
        hid[t] = fmaxf(a, 0.f);
    }
    __syncthreads();

    if (t < 10) {
        float a = bf2[t];
        #pragma unroll
        for (int k = 0; k < 32; ++k) a += hid[k] * Wf2[k * 10 + t];
        out[g * 10 + t] = a;
    }
}

// ---------------- launcher ----------------

extern "C" void kernel_launch(void* const* d_in, const int* in_sizes, int n_in,
                              void* d_out, int out_size, void* d_ws, size_t ws_size,
                              hipStream_t stream) {
    const float* x     = (const float*)d_in[0];
    const int*   edge  = (const int*)  d_in[1];
    const int*   batch = (const int*)  d_in[2];
    const float* W1    = (const float*)d_in[3];
    const float* b1    = (const float*)d_in[4];
    const float* W2    = (const float*)d_in[5];
    const float* b2    = (const float*)d_in[6];
    const float* W3    = (const float*)d_in[7];
    const float* b3    = (const float*)d_in[8];
    const float* Wf1   = (const float*)d_in[9];
    const float* bf1   = (const float*)d_in[10];
    const float* Wf2   = (const float*)d_in[11];
    const float* bf2   = (const float*)d_in[12];
    float* out = (float*)d_out;

    const int E = in_sizes[1] / 2;     // 800000
    const int n = in_sizes[2];         // 50000
    const int* row = edge;
    const int* col = edge + E;

    const int colsPerGroup = (n + 7) / 8;                  // 6250

    const size_t n_pad = ((size_t)n + 64) & ~(size_t)63;
    char* wsb = (char*)d_ws;
    int*    cnt    = (int*)wsb;                  wsb += n_pad * 4;            // degree
    float*  pooled = (float*)wsb;                wsb += NGRAPH * 64 * 4;
    int*    bucket = (int*)wsb;                  wsb += (size_t)n_pad * CAP * 4;  // 12.8 MB
    __half* Wt1    = (__half*)wsb;               wsb += 16384 * 2;
    __half* Wt2    = (__half*)wsb;               wsb += 16384 * 2;
    __half* Wt3    = (__half*)wsb;               wsb += 8192 * 2;
    __half* bufA   = (__half*)wsb;               wsb += (size_t)n * 128 * 2;  // 12.8 MB
    __half* bufB   = (__half*)wsb;                                            // 12.8 MB

    // ---- prep + bucket build ----
    prep_all<<<256, 256, 0, stream>>>(W1, W2, W3, Wt1, Wt2, Wt3, cnt, pooled, n);
    fill_bucket<<<1024, 256, 0, stream>>>(row, col, cnt, bucket, E, colsPerGroup);

    const int ggemm = (n + 63) / 64;                       // 64 rows per block
    const int gath_grid = (n * 64 + 255) / 256;            // one wave per node

    // layer 1 (fp32 input)
    gemm_mfma<128, false><<<ggemm, 256, 0, stream>>>(x, Wt1, nullptr, cnt, bufA, n);
    gather_kernel<128><<<gath_grid, 256, 0, stream>>>(bufA, cnt, bucket, bufB, n);
    // layer 2 (fp16 input)
    gemm_mfma<128, true><<<ggemm, 256, 0, stream>>>(bufB, Wt2, b1, cnt, bufA, n);
    gather_kernel<128><<<gath_grid, 256, 0, stream>>>(bufA, cnt, bucket, bufB, n);
    // layer 3 (64-wide, fp16 input)
    gemm_mfma<64, true><<<ggemm, 256, 0, stream>>>(bufB, Wt3, b2, cnt, bufA, n);
    // head: gather64 + relu(+b3) + mean-pool fused; then MLP
    fused_gpool<<<2048, 256, 0, stream>>>(bufA, cnt, bucket, b3, batch, pooled, n);
    mlp_kernel<<<NGRAPH, 64, 0, stream>>>(pooled, batch, Wf1, bf1, Wf2, bf2, out, n);
}